// Round 2
// baseline (615.239 us; speedup 1.0000x reference)
//
#include <hip/hip_runtime.h>
#include <hip/hip_bf16.h>
#include <math.h>

#define B_BATCH 8
#define SEQ 2048
#define DIM 768
#define E3 2304   // 3*DIM

typedef __bf16 bf16x8 __attribute__((ext_vector_type(8)));
typedef float floatx4 __attribute__((ext_vector_type(4)));

__device__ __forceinline__ void load_lds_16B(const __hip_bfloat16* g, __hip_bfloat16* l) {
    __builtin_amdgcn_global_load_lds((const __attribute__((address_space(1))) void*)g,
                                     (__attribute__((address_space(3))) void*)l, 16, 0, 0);
}

#define MEMFENCE asm volatile("" ::: "memory")
#define BAR() do { MEMFENCE; __builtin_amdgcn_s_barrier(); MEMFENCE; } while (0)
#define WAITVM(N) asm volatile("s_waitcnt vmcnt(" #N ")" ::: "memory")

template<typename T> __device__ __forceinline__ T to_out(float v);
template<> __device__ __forceinline__ float to_out<float>(float v) { return v; }
template<> __device__ __forceinline__ __hip_bfloat16 to_out<__hip_bfloat16>(float v) { return __float2bfloat16(v); }

// fp32 -> bf16 conversion, 8 elements per thread
__global__ __launch_bounds__(256, 4)
void cvt_f32_bf16(const float* __restrict__ in, __hip_bfloat16* __restrict__ out, long n8)
{
    const long i = (long)blockIdx.x * blockDim.x + threadIdx.x;
    if (i >= n8) return;
    const float4* p = (const float4*)in + i * 2;
    const float4 a = p[0], b = p[1];
    union { uint4 u; __hip_bfloat16 h[8]; } t;
    t.h[0] = __float2bfloat16(a.x); t.h[1] = __float2bfloat16(a.y);
    t.h[2] = __float2bfloat16(a.z); t.h[3] = __float2bfloat16(a.w);
    t.h[4] = __float2bfloat16(b.x); t.h[5] = __float2bfloat16(b.y);
    t.h[6] = __float2bfloat16(b.z); t.h[7] = __float2bfloat16(b.w);
    ((uint4*)out)[i] = t.u;
}

// 64x64 LDS-tiled transpose: out[c][r] = in[r][c].  grid (rows/64, cols/64, Z)
__global__ __launch_bounds__(256, 4)
void transpose64(const __hip_bfloat16* __restrict__ in, long ldi, long si,
                 __hip_bfloat16* __restrict__ out, long ldo, long so)
{
    __shared__ __hip_bfloat16 t[64][65];   // +1 pad
    in  += (long)blockIdx.z * si;
    out += (long)blockIdx.z * so;
    const int r0 = blockIdx.x * 64;
    const int c0 = blockIdx.y * 64;
    const int tid = threadIdx.x;
    const int r  = tid >> 3;
    const int c8 = (tid & 7) * 8;
#pragma unroll
    for (int h = 0; h < 2; ++h) {
        const int row = r + h * 32;
        union { uint4 u; __hip_bfloat16 v[8]; } tmp;
        tmp.u = *(const uint4*)(in + (long)(r0 + row) * ldi + c0 + c8);
#pragma unroll
        for (int j = 0; j < 8; ++j) t[row][c8 + j] = tmp.v[j];
    }
    __syncthreads();
#pragma unroll
    for (int h = 0; h < 2; ++h) {
        const int cr = r + h * 32;
        union { uint4 u; __hip_bfloat16 v[8]; } tmp;
#pragma unroll
        for (int j = 0; j < 8; ++j) tmp.v[j] = t[c8 + j][cr];
        *(uint4*)(out + (long)(c0 + cr) * ldo + r0 + c8) = tmp.u;
    }
}

// ---------------- 256x256 8-phase GEMM (T1+T2+T3/T4+T5) ----------------
// C[M x N] = f( A [M x K] * B^T ), B is [N x K] row-major.
// EPI = 0: C = scale*AB^T + bias
// EPI = 1: C = exp(scale*AB^T)      (|scale*s| < ~1 for this problem)
// EPI = 2: C = (AB^T) / rowsum(A)   (rowsum accumulated from A-fragments in-loop)
//
// LDS = exactly 128 KiB (SA+SB; lsum aliases SA after the K-loop — SA is dead
// there, last read completes before the final ph8 barrier).
//
// LDS: SA/SB = [2 bufs][256 rows][64 cols] bf16, XOR-swizzled:
//   LDS(row, chunk16B c) holds global chunk c ^ (row & 7).
//   global_load_lds writes linearly (uniform base + lane*16B); the lane's GLOBAL
//   source is pre-swizzled so the read side can XOR the same involution (rule #21).
//
// Stage schedule per iteration i (tiles t0=2i in SA/SB[0], t0+1 in [1]):
//   ph1: A1,B1(t0+1)  ph3: A0(t0+2)  ph4: B0(t0+2)  ph5: A1,B1(t0+2)
//   ph7: A0(t0+3)     ph8: B0(t0+3)
// Each stage targets a slot whose last ds_read was >=1 full barrier earlier
// (frag reads: A0,B0@ph1, B1@ph2, A1@ph3 per tile).  vmcnt(4) at ph4 proves
// tile t0+1 fully landed (4 newer loads = ph3+ph4); vmcnt(4) at ph8 proves
// t0+2 landed (4 newer = ph7+ph8).  Last iteration: ph3..ph8 stages suppressed
// -> ph4 must use vmcnt(0).  Grid is always a multiple of 8 (XCD bijection).
__device__ __forceinline__ void stage_half(const __hip_bfloat16* __restrict__ G, long ld,
        int R0, int t, int h, __hip_bfloat16* lbuf, int wid, int lane)
{
    const int cs = ((lane & 7) ^ (lane >> 3)) << 3;      // pre-swizzled col (elems)
#pragma unroll
    for (int q = 0; q < 2; ++q) {
        const int r = (q * 8 + wid) * 8 + (lane >> 3);   // row within half
        load_lds_16B(G + (long)(R0 + h * 128 + r) * ld + t * 64 + cs,
                     lbuf + h * 8192 + (q * 8 + wid) * 512);   // wave-uniform base
    }
}

__device__ __forceinline__ bf16x8 ldfrag(const __hip_bfloat16* buf, int r, int kk, int g)
{
    const int o = r * 128 + ((kk * 64 + g * 16) ^ ((r & 7) << 4));
    return *(const bf16x8*)((const char*)buf + o);
}

template<int QM>
__device__ __forceinline__ void loadA(const __hip_bfloat16* SAb, bf16x8 (&af)[4][2],
                                      int wrow, int fr, int g)
{
#pragma unroll
    for (int mi = 0; mi < 4; ++mi)
#pragma unroll
        for (int kk = 0; kk < 2; ++kk)
            af[mi][kk] = ldfrag(SAb, QM * 128 + wrow * 64 + mi * 16 + fr, kk, g);
}

template<int QN>
__device__ __forceinline__ void loadB(const __hip_bfloat16* SBb, bf16x8 (&bf)[2][2],
                                      int wcol, int fr, int g)
{
#pragma unroll
    for (int ni = 0; ni < 2; ++ni)
#pragma unroll
        for (int kk = 0; kk < 2; ++kk)
            bf[ni][kk] = ldfrag(SBb, QN * 128 + wcol * 32 + ni * 16 + fr, kk, g);
}

__device__ __forceinline__ void mfma16(const bf16x8 (&af)[4][2], const bf16x8 (&bf)[2][2],
                                       floatx4 (&ac)[4][2])
{
#pragma unroll
    for (int mi = 0; mi < 4; ++mi)
#pragma unroll
        for (int ni = 0; ni < 2; ++ni)
#pragma unroll
            for (int kk = 0; kk < 2; ++kk)
                ac[mi][ni] = __builtin_amdgcn_mfma_f32_16x16x32_bf16(
                    af[mi][kk], bf[ni][kk], ac[mi][ni], 0, 0, 0);
}

__device__ __forceinline__ void rsum_acc(const bf16x8 (&af)[4][2], float (&rs)[4])
{
#pragma unroll
    for (int mi = 0; mi < 4; ++mi) {
        float s = 0.f;
#pragma unroll
        for (int kk = 0; kk < 2; ++kk)
#pragma unroll
            for (int j = 0; j < 8; ++j)
                s += (float)af[kk == 0 ? mi : mi][kk][j];
        rs[mi] += s;
    }
}

template<typename OutT, int EPI>
__global__ __launch_bounds__(512, 2)
void gemm256(const __hip_bfloat16* __restrict__ A, long lda, long sA,
             const __hip_bfloat16* __restrict__ Bm, long ldb, long sB,
             OutT* __restrict__ C, long ldc, long sC,
             const float* __restrict__ bias, float scale, int K,
             int MB, int NB)
{
    __shared__ __hip_bfloat16 SA[2][256 * 64];   // 64 KB
    __shared__ __hip_bfloat16 SB[2][256 * 64];   // 64 KB  -> total exactly 128 KiB
    float* lsum = (float*)&SA[0][0];             // EPI==2 scratch; SA dead post-loop

    // bijective XCD swizzle (every grid here is a multiple of 8)
    const int nwg  = gridDim.x;
    const int orig = blockIdx.x;
    const int wgid = (orig & 7) * (nwg >> 3) + (orig >> 3);
    const int zblk = wgid / (MB * NB);
    const int rem  = wgid - zblk * (MB * NB);
    const int mblk = rem / NB;
    const int nblk = rem - mblk * NB;

    A  += (long)zblk * sA;
    Bm += (long)zblk * sB;
    C  += (long)zblk * sC;
    const int m0 = mblk * 256, n0 = nblk * 256;

    const int tid  = threadIdx.x;
    const int wid  = tid >> 6, lane = tid & 63;
    const int wrow = wid >> 2, wcol = wid & 3;     // 2 (M) x 4 (N) waves
    const int fr   = lane & 15, g = lane >> 4;

    floatx4 acc[2][2][4][2] = {};                  // [qm][qn][mi][ni]
    float   rsum[2][4] = {};
    bf16x8  af[4][2], bfr[2][2][2];                // A: current qm; B: both qn held

    const int NI = K >> 7;                         // iterations (2 tiles of BK=64 each)

    // prologue: tile0 fully + tile1 half0; vmcnt(4) proves tile0 landed
    stage_half(A,  lda, m0, 0, 0, SA[0], wid, lane);
    stage_half(A,  lda, m0, 0, 1, SA[0], wid, lane);
    stage_half(Bm, ldb, n0, 0, 0, SB[0], wid, lane);
    stage_half(Bm, ldb, n0, 0, 1, SB[0], wid, lane);
    stage_half(A,  lda, m0, 1, 0, SA[1], wid, lane);
    stage_half(Bm, ldb, n0, 1, 0, SB[1], wid, lane);
    WAITVM(4);
    BAR();

    for (int i = 0; i < NI; ++i) {
        const int  t0   = 2 * i;
        const bool last = (i == NI - 1);

        // ph1 (qm0,qn0) buf0 — stage A1,B1 of t0+1
        loadA<0>(SA[0], af, wrow, fr, g);
        loadB<0>(SB[0], bfr[0], wcol, fr, g);
        stage_half(A,  lda, m0, t0 + 1, 1, SA[1], wid, lane);
        stage_half(Bm, ldb, n0, t0 + 1, 1, SB[1], wid, lane);
        BAR();
        __builtin_amdgcn_s_setprio(1);
        mfma16(af, bfr[0], acc[0][0]);
        __builtin_amdgcn_s_setprio(0);
        if constexpr (EPI == 2) rsum_acc(af, rsum[0]);
        BAR();

        // ph2 (qm0,qn1) buf0
        loadB<1>(SB[0], bfr[1], wcol, fr, g);
        BAR();
        __builtin_amdgcn_s_setprio(1);
        mfma16(af, bfr[1], acc[0][1]);
        __builtin_amdgcn_s_setprio(0);
        BAR();

        // ph3 (qm1,qn0) buf0 — stage A0 of t0+2 (slot free since ph1)
        loadA<1>(SA[0], af, wrow, fr, g);
        if (!last) stage_half(A, lda, m0, t0 + 2, 0, SA[0], wid, lane);
        BAR();
        __builtin_amdgcn_s_setprio(1);
        mfma16(af, bfr[0], acc[1][0]);
        __builtin_amdgcn_s_setprio(0);
        if constexpr (EPI == 2) rsum_acc(af, rsum[1]);
        BAR();

        // ph4 (qm1,qn1) buf0 — stage B0 of t0+2; counted vmcnt proves t0+1 landed
        if (!last) stage_half(Bm, ldb, n0, t0 + 2, 0, SB[0], wid, lane);
        BAR();
        __builtin_amdgcn_s_setprio(1);
        mfma16(af, bfr[1], acc[1][1]);
        __builtin_amdgcn_s_setprio(0);
        if (!last) { WAITVM(4); } else { WAITVM(0); }
        BAR();

        // ph5 (qm0,qn0) buf1 — stage A1,B1 of t0+2
        loadA<0>(SA[1], af, wrow, fr, g);
        loadB<0>(SB[1], bfr[0], wcol, fr, g);
        if (!last) {
            stage_half(A,  lda, m0, t0 + 2, 1, SA[0], wid, lane);
            stage_half(Bm, ldb, n0, t0 + 2, 1, SB[0], wid, lane);
        }
        BAR();
        __builtin_amdgcn_s_setprio(1);
        mfma16(af, bfr[0], acc[0][0]);
        __builtin_amdgcn_s_setprio(0);
        if constexpr (EPI == 2) rsum_acc(af, rsum[0]);
        BAR();

        // ph6 (qm0,qn1) buf1
        loadB<1>(SB[1], bfr[1], wcol, fr, g);
        BAR();
        __builtin_amdgcn_s_setprio(1);
        mfma16(af, bfr[1], acc[0][1]);
        __builtin_amdgcn_s_setprio(0);
        BAR();

        // ph7 (qm1,qn0) buf1 — stage A0 of t0+3
        loadA<1>(SA[1], af, wrow, fr, g);
        if (!last) stage_half(A, lda, m0, t0 + 3, 0, SA[1], wid, lane);
        BAR();
        __builtin_amdgcn_s_setprio(1);
        mfma16(af, bfr[0], acc[1][0]);
        __builtin_amdgcn_s_setprio(0);
        if constexpr (EPI == 2) rsum_acc(af, rsum[1]);
        BAR();

        // ph8 (qm1,qn1) buf1 — stage B0 of t0+3; counted vmcnt proves t0+2 landed
        if (!last) stage_half(Bm, ldb, n0, t0 + 3, 0, SB[1], wid, lane);
        BAR();
        __builtin_amdgcn_s_setprio(1);
        mfma16(af, bfr[1], acc[1][1]);
        __builtin_amdgcn_s_setprio(0);
        if (!last) WAITVM(4);
        BAR();
    }

    if constexpr (EPI == 2) {
#pragma unroll
        for (int qm = 0; qm < 2; ++qm)
#pragma unroll
            for (int mi = 0; mi < 4; ++mi) {
                rsum[qm][mi] += __shfl_xor(rsum[qm][mi], 16, 64);
                rsum[qm][mi] += __shfl_xor(rsum[qm][mi], 32, 64);
            }
        if (wcol == 0 && g == 0) {
#pragma unroll
            for (int qm = 0; qm < 2; ++qm)
#pragma unroll
                for (int mi = 0; mi < 4; ++mi)
                    lsum[qm * 128 + wrow * 64 + mi * 16 + fr] = rsum[qm][mi];
        }
        __syncthreads();   // vmcnt already drained; full sync is fine here
    }

    // C/D layout: col = lane&15, row = (lane>>4)*4 + reg  [verified m89/m91]
    const int cr = g * 4;
    float inv[2][4][4];
    if constexpr (EPI == 2) {
#pragma unroll
        for (int qm = 0; qm < 2; ++qm)
#pragma unroll
            for (int mi = 0; mi < 4; ++mi)
#pragma unroll
                for (int r = 0; r < 4; ++r)
                    inv[qm][mi][r] = 1.0f / lsum[qm * 128 + wrow * 64 + mi * 16 + cr + r];
    }

#pragma unroll
    for (int qn = 0; qn < 2; ++qn)
#pragma unroll
    for (int ni = 0; ni < 2; ++ni) {
        const int col = n0 + qn * 128 + wcol * 32 + ni * 16 + fr;
        const float bv = (EPI == 0 && bias) ? bias[col] : 0.0f;
#pragma unroll
        for (int qm = 0; qm < 2; ++qm)
#pragma unroll
        for (int mi = 0; mi < 4; ++mi)
#pragma unroll
        for (int r = 0; r < 4; ++r) {
            const int row = m0 + qm * 128 + wrow * 64 + mi * 16 + cr + r;
            float v = acc[qm][qn][mi][ni][r];
            if constexpr (EPI == 0)      v = v * scale + bv;
            else if constexpr (EPI == 1) v = __expf(v * scale);
            else                         v = v * inv[qm][mi][r];
            C[(long)row * ldc + col] = to_out<OutT>(v);
        }
    }
}

extern "C" void kernel_launch(void* const* d_in, const int* in_sizes, int n_in,
                              void* d_out, int out_size, void* d_ws, size_t ws_size,
                              hipStream_t stream)
{
    const float* x     = (const float*)d_in[0];
    const float* w_qkv = (const float*)d_in[1];
    const float* b_qkv = (const float*)d_in[2];
    const float* w_prj = (const float*)d_in[3];
    const float* b_prj = (const float*)d_in[4];
    float* out = (float*)d_out;

    const float alpha = 1.0f / (sqrtf((float)DIM) * 3.0f);  // qk scale / temperature

    const size_t XE   = (size_t)B_BATCH * SEQ * DIM;
    const size_t WQE  = (size_t)E3 * DIM;
    const size_t WPE  = (size_t)DIM * DIM;
    const size_t QKVE = (size_t)B_BATCH * SEQ * E3;
    const size_t SE   = (size_t)B_BATCH * SEQ * SEQ;
    const size_t OE   = XE;
    dim3 blk(256), blkg(512);

    const size_t full_bytes = (XE + WQE + WPE + QKVE + SE + OE) * sizeof(__hip_bfloat16);

    if (ws_size >= full_bytes) {
        __hip_bfloat16* xb  = (__hip_bfloat16*)d_ws;
        __hip_bfloat16* wqb = xb + XE;
        __hip_bfloat16* wpb = wqb + WQE;
        __hip_bfloat16* qkv = wpb + WPE;
        __hip_bfloat16* S   = qkv + QKVE;
        __hip_bfloat16* O   = S + SE;
        __hip_bfloat16* Vt  = xb;                      // xb dead after QKV GEMM

        cvt_f32_bf16<<<dim3((XE / 8 + 255) / 256), blk, 0, stream>>>(x, xb, XE / 8);
        cvt_f32_bf16<<<dim3((WQE / 8 + 255) / 256), blk, 0, stream>>>(w_qkv, wqb, WQE / 8);
        cvt_f32_bf16<<<dim3((WPE / 8 + 255) / 256), blk, 0, stream>>>(w_prj, wpb, WPE / 8);

        // qkv = x @ w_qkv^T + b   [16384 x 2304]  grid 64*9=576
        gemm256<__hip_bfloat16, 0><<<dim3(64 * 9), blkg, 0, stream>>>(
            xb, DIM, 0, wqb, DIM, 0, qkv, E3, 0, b_qkv, 1.0f, DIM, 64, 9);
        // Vt[b] = V[b]^T  [768 x 2048] per batch
        transpose64<<<dim3(SEQ / 64, DIM / 64, B_BATCH), blk, 0, stream>>>(
            qkv + 2 * DIM, E3, (long)SEQ * E3, Vt, SEQ, (long)DIM * SEQ);
        // E = exp(alpha * Q @ K^T)  [8][2048 x 2048]  grid 8*8*8=512
        gemm256<__hip_bfloat16, 1><<<dim3(8 * 8 * B_BATCH), blkg, 0, stream>>>(
            qkv, E3, (long)SEQ * E3, qkv + DIM, E3, (long)SEQ * E3,
            S, SEQ, (long)SEQ * SEQ, nullptr, alpha, DIM, 8, 8);
        // O = (E @ Vt^T) / rowsum(E)  [8][2048 x 768]  grid 8*3*8=192
        gemm256<__hip_bfloat16, 2><<<dim3(8 * 3 * B_BATCH), blkg, 0, stream>>>(
            S, SEQ, (long)SEQ * SEQ, Vt, SEQ, (long)DIM * SEQ,
            O, DIM, (long)SEQ * DIM, nullptr, 1.0f, SEQ, 8, 3);
        // out = O @ w_proj^T + b  [16384 x 768] fp32  grid 64*3=192
        gemm256<float, 0><<<dim3(64 * 3), blkg, 0, stream>>>(
            O, DIM, 0, wpb, DIM, 0, out, DIM, 0, b_prj, 1.0f, DIM, 64, 3);
    } else {
        // minimal-workspace fallback: per-batch pipeline (~30 MB scratch)
        const size_t xE  = (size_t)SEQ * DIM;
        const size_t qE  = (size_t)SEQ * E3;
        const size_t sE1 = (size_t)SEQ * SEQ;
        __hip_bfloat16* wqb = (__hip_bfloat16*)d_ws;
        __hip_bfloat16* wpb = wqb + WQE;
        __hip_bfloat16* xb  = wpb + WPE;
        __hip_bfloat16* qkv = xb + xE;
        __hip_bfloat16* S   = qkv + qE;
        __hip_bfloat16* O   = S + sE1;
        __hip_bfloat16* Vt  = xb;

        cvt_f32_bf16<<<dim3((WQE / 8 + 255) / 256), blk, 0, stream>>>(w_qkv, wqb, WQE / 8);
        cvt_f32_bf16<<<dim3((WPE / 8 + 255) / 256), blk, 0, stream>>>(w_prj, wpb, WPE / 8);

        for (int b = 0; b < B_BATCH; ++b) {
            const float* xf = x + (size_t)b * xE;
            cvt_f32_bf16<<<dim3((xE / 8 + 255) / 256), blk, 0, stream>>>(xf, xb, xE / 8);
            gemm256<__hip_bfloat16, 0><<<dim3(8 * 9), blkg, 0, stream>>>(
                xb, DIM, 0, wqb, DIM, 0, qkv, E3, 0, b_qkv, 1.0f, DIM, 8, 9);
            transpose64<<<dim3(SEQ / 64, DIM / 64, 1), blk, 0, stream>>>(
                qkv + 2 * DIM, E3, 0, Vt, SEQ, 0);
            gemm256<__hip_bfloat16, 1><<<dim3(8 * 8), blkg, 0, stream>>>(
                qkv, E3, 0, qkv + DIM, E3, 0, S, SEQ, 0, nullptr, alpha, DIM, 8, 8);
            gemm256<__hip_bfloat16, 2><<<dim3(8 * 3), blkg, 0, stream>>>(
                S, SEQ, 0, Vt, SEQ, 0, O, DIM, 0, nullptr, 1.0f, SEQ, 8, 3);
            gemm256<float, 0><<<dim3(8 * 3), blkg, 0, stream>>>(
                O, DIM, 0, wpb, DIM, 0, out + (size_t)b * xE, DIM, 0, b_prj, 1.0f, DIM, 8, 3);
        }
    }
}

// Round 3
// 394.178 us; speedup vs baseline: 1.5608x; 1.5608x over previous
//
#include <hip/hip_runtime.h>
#include <hip/hip_bf16.h>
#include <math.h>

#define B_BATCH 8
#define SEQ 2048
#define DIM 768
#define E3 2304   // 3*DIM

typedef __bf16 bf16x8 __attribute__((ext_vector_type(8)));
typedef float floatx4 __attribute__((ext_vector_type(4)));

__device__ __forceinline__ void load_lds_16B(const __hip_bfloat16* g, __hip_bfloat16* l) {
    __builtin_amdgcn_global_load_lds((const __attribute__((address_space(1))) void*)g,
                                     (__attribute__((address_space(3))) void*)l, 16, 0, 0);
}

#define MEMFENCE asm volatile("" ::: "memory")
#define BAR() do { MEMFENCE; __builtin_amdgcn_s_barrier(); MEMFENCE; } while (0)
#define WAITVM(N) asm volatile("s_waitcnt vmcnt(" #N ")" ::: "memory")

template<typename T> __device__ __forceinline__ T to_out(float v);
template<> __device__ __forceinline__ float to_out<float>(float v) { return v; }
template<> __device__ __forceinline__ __hip_bfloat16 to_out<__hip_bfloat16>(float v) { return __float2bfloat16(v); }

// fp32 -> bf16 conversion, 8 elements per thread
__global__ __launch_bounds__(256, 4)
void cvt_f32_bf16(const float* __restrict__ in, __hip_bfloat16* __restrict__ out, long n8)
{
    const long i = (long)blockIdx.x * blockDim.x + threadIdx.x;
    if (i >= n8) return;
    const float4* p = (const float4*)in + i * 2;
    const float4 a = p[0], b = p[1];
    union { uint4 u; __hip_bfloat16 h[8]; } t;
    t.h[0] = __float2bfloat16(a.x); t.h[1] = __float2bfloat16(a.y);
    t.h[2] = __float2bfloat16(a.z); t.h[3] = __float2bfloat16(a.w);
    t.h[4] = __float2bfloat16(b.x); t.h[5] = __float2bfloat16(b.y);
    t.h[6] = __float2bfloat16(b.z); t.h[7] = __float2bfloat16(b.w);
    ((uint4*)out)[i] = t.u;
}

// 64x64 LDS-tiled transpose: out[c][r] = in[r][c].  grid (rows/64, cols/64, Z)
__global__ __launch_bounds__(256, 4)
void transpose64(const __hip_bfloat16* __restrict__ in, long ldi, long si,
                 __hip_bfloat16* __restrict__ out, long ldo, long so)
{
    __shared__ __hip_bfloat16 t[64][65];   // +1 pad
    in  += (long)blockIdx.z * si;
    out += (long)blockIdx.z * so;
    const int r0 = blockIdx.x * 64;
    const int c0 = blockIdx.y * 64;
    const int tid = threadIdx.x;
    const int r  = tid >> 3;
    const int c8 = (tid & 7) * 8;
#pragma unroll
    for (int h = 0; h < 2; ++h) {
        const int row = r + h * 32;
        union { uint4 u; __hip_bfloat16 v[8]; } tmp;
        tmp.u = *(const uint4*)(in + (long)(r0 + row) * ldi + c0 + c8);
#pragma unroll
        for (int j = 0; j < 8; ++j) t[row][c8 + j] = tmp.v[j];
    }
    __syncthreads();
#pragma unroll
    for (int h = 0; h < 2; ++h) {
        const int cr = r + h * 32;
        union { uint4 u; __hip_bfloat16 v[8]; } tmp;
#pragma unroll
        for (int j = 0; j < 8; ++j) tmp.v[j] = t[c8 + j][cr];
        *(uint4*)(out + (long)(c0 + cr) * ldo + r0 + c8) = tmp.u;
    }
}

// ---------------- 256x256 8-phase GEMM, register-dieted ----------------
// C[M x N] = f( A [M x K] * B^T ), B is [N x K] row-major.
// EPI = 0: C = scale*AB^T + bias
// EPI = 1: C = exp(scale*AB^T); per-row sums of fp32 exp atomically added to rs[]
// EPI = 2: C = (AB^T) * (1/rs[row])   (rs precomputed by the EPI=1 launch)
//
// Register budget (512-thr block => hard cap 256 unified regs/wave):
//   acc 128 + af 32 + bf 16 + addressing ~20  ≈ 200.  v1 spilled (438 MB
//   scratch writes on the PV dispatch); this version drops the dual-B hold
//   (snake qn order 0,1,1,0) and the EPI2 in-loop row-sum.
//
// Snake phases per tile: a(qm0,qn0: loadA0,loadB0) b(qm0,qn1: loadB1)
//   c(qm1,qn1: loadA1, B held) d(qm1,qn0: loadB0 again).
// Stage schedule per iteration i (t0=2i in buf0, t0+1 in buf1):
//   a: {A-h1,B-h0}(t0+1->buf1)   c: A-h0(t0+2->buf0)  d: B-h1(t0+2->buf0)
//   e: {A-h1,B-h0}(t0+2->buf0)   g: A-h0(t0+3->buf1)  h: B-h1(t0+3->buf1)
//   prologue stages t0 full + {A-h0,B-h1}(t1).
// Every staged region's last ds_read is >=1 closing-barrier upstream (readers'
// lgkmcnt(0) precedes the barrier, so the region is quiescent).  vmcnt(4) at
// d/h closes drain exactly the 8 loads of the next-needed tile; last iteration
// uses vmcnt(0) at d (no further stages).  Grid always %8==0 (XCD bijection).
__device__ __forceinline__ bf16x8 ldfrag(const __hip_bfloat16* buf, int r, int kk, int g)
{
    const int o = r * 128 + ((kk * 64 + g * 16) ^ ((r & 7) << 4));
    return *(const bf16x8*)((const char*)buf + o);
}

template<int QM>
__device__ __forceinline__ void loadA(const __hip_bfloat16* SAb, bf16x8 (&af)[4][2],
                                      int wrow, int fr, int g)
{
#pragma unroll
    for (int mi = 0; mi < 4; ++mi)
#pragma unroll
        for (int kk = 0; kk < 2; ++kk)
            af[mi][kk] = ldfrag(SAb, QM * 128 + wrow * 64 + mi * 16 + fr, kk, g);
}

template<int QN>
__device__ __forceinline__ void loadB(const __hip_bfloat16* SBb, bf16x8 (&bf)[2][2],
                                      int wcol, int fr, int g)
{
#pragma unroll
    for (int ni = 0; ni < 2; ++ni)
#pragma unroll
        for (int kk = 0; kk < 2; ++kk)
            bf[ni][kk] = ldfrag(SBb, QN * 128 + wcol * 32 + ni * 16 + fr, kk, g);
}

__device__ __forceinline__ void mfma16(const bf16x8 (&af)[4][2], const bf16x8 (&bf)[2][2],
                                       floatx4 (&ac)[4][2])
{
#pragma unroll
    for (int mi = 0; mi < 4; ++mi)
#pragma unroll
        for (int ni = 0; ni < 2; ++ni)
#pragma unroll
            for (int kk = 0; kk < 2; ++kk)
                ac[mi][ni] = __builtin_amdgcn_mfma_f32_16x16x32_bf16(
                    af[mi][kk], bf[ni][kk], ac[mi][ni], 0, 0, 0);
}

template<typename OutT, int EPI>
__global__ __launch_bounds__(512, 2)
void gemm256(const __hip_bfloat16* __restrict__ A, long lda, long sA,
             const __hip_bfloat16* __restrict__ Bm, long ldb, long sB,
             OutT* __restrict__ C, long ldc, long sC,
             const float* __restrict__ bias,
             float* __restrict__ rs, long srs,
             float scale, int K, int MB, int NB)
{
    __shared__ __hip_bfloat16 SA[2][256 * 64];   // 64 KB
    __shared__ __hip_bfloat16 SB[2][256 * 64];   // 64 KB  -> exactly 128 KiB

    // bijective XCD swizzle (every grid here is a multiple of 8)
    const int nwg  = gridDim.x;
    const int orig = blockIdx.x;
    const int wgid = (orig & 7) * (nwg >> 3) + (orig >> 3);
    const int zblk = wgid / (MB * NB);
    const int rem  = wgid - zblk * (MB * NB);
    const int mblk = rem / NB;
    const int nblk = rem - mblk * NB;

    A  += (long)zblk * sA;
    Bm += (long)zblk * sB;
    C  += (long)zblk * sC;
    if constexpr (EPI != 0) rs += (long)zblk * srs;
    const int m0 = mblk * 256, n0 = nblk * 256;

    const int tid  = threadIdx.x;
    const int wid  = tid >> 6, lane = tid & 63;
    const int wrow = wid >> 2, wcol = wid & 3;     // 2 (M) x 4 (N) waves
    const int fr   = lane & 15, g = lane >> 4;

    // --- precomputed per-lane staging offsets (elements) ---
    const int cs   = ((lane & 7) ^ (lane >> 3)) << 3;       // pre-swizzled col
    const int rA0  = (wid) * 8 + (lane >> 3);               // q=0 row
    const int rA1  = (8 + wid) * 8 + (lane >> 3);           // q=1 row
    const int loffA0 = rA0 * (int)lda + cs, loffA1 = rA1 * (int)lda + cs;
    const int loffB0 = rA0 * (int)ldb + cs, loffB1 = rA1 * (int)ldb + cs;
    const int hA = 128 * (int)lda, hB = 128 * (int)ldb;     // half-tile row jump
    const __hip_bfloat16* Ag = A + (long)m0 * lda;
    const __hip_bfloat16* Bg = Bm + (long)n0 * ldb;

    // stage one (matrix, half, tile) -> 2 global_load_lds
#define STG_A(h, t, buf) do { \
        const __hip_bfloat16* _b = Ag + (h) * hA + (t) * 64; \
        __hip_bfloat16* _l = &SA[buf][0] + (h) * 8192 + wid * 512; \
        load_lds_16B(_b + loffA0, _l); \
        load_lds_16B(_b + loffA1, _l + 4096); \
    } while (0)
#define STG_B(h, t, buf) do { \
        const __hip_bfloat16* _b = Bg + (h) * hB + (t) * 64; \
        __hip_bfloat16* _l = &SB[buf][0] + (h) * 8192 + wid * 512; \
        load_lds_16B(_b + loffB0, _l); \
        load_lds_16B(_b + loffB1, _l + 4096); \
    } while (0)

    floatx4 acc[2][2][4][2] = {};                  // [qm][qn][mi][ni]
    bf16x8  af[4][2], bf[2][2];

    const int NI = K >> 7;                         // 2 tiles of BK=64 per iter

    // prologue: t0 full + {A-h0, B-h1} of t1; vmcnt(4) proves t0 landed
    STG_A(0, 0, 0); STG_A(1, 0, 0);
    STG_B(0, 0, 0); STG_B(1, 0, 0);
    STG_A(0, 1, 1); STG_B(1, 1, 1);
    WAITVM(4);
    BAR();

    for (int i = 0; i < NI; ++i) {
        const int  t0   = 2 * i;
        const bool last = (i == NI - 1);

        // ph a (qm0,qn0) buf0 — stage {A-h1,B-h0}(t0+1 -> buf1)
        loadA<0>(SA[0], af, wrow, fr, g);
        loadB<0>(SB[0], bf, wcol, fr, g);
        STG_A(1, t0 + 1, 1); STG_B(0, t0 + 1, 1);
        BAR();
        __builtin_amdgcn_s_setprio(1);
        mfma16(af, bf, acc[0][0]);
        __builtin_amdgcn_s_setprio(0);
        BAR();

        // ph b (qm0,qn1) buf0
        loadB<1>(SB[0], bf, wcol, fr, g);
        BAR();
        __builtin_amdgcn_s_setprio(1);
        mfma16(af, bf, acc[0][1]);
        __builtin_amdgcn_s_setprio(0);
        BAR();

        // ph c (qm1,qn1) buf0 (B held) — stage A-h0(t0+2 -> buf0)
        loadA<1>(SA[0], af, wrow, fr, g);
        if (!last) STG_A(0, t0 + 2, 0);
        BAR();
        __builtin_amdgcn_s_setprio(1);
        mfma16(af, bf, acc[1][1]);
        __builtin_amdgcn_s_setprio(0);
        BAR();

        // ph d (qm1,qn0) buf0 — stage B-h1(t0+2 -> buf0); drain next tile's 8
        loadB<0>(SB[0], bf, wcol, fr, g);
        if (!last) STG_B(1, t0 + 2, 0);
        BAR();
        __builtin_amdgcn_s_setprio(1);
        mfma16(af, bf, acc[1][0]);
        __builtin_amdgcn_s_setprio(0);
        if (!last) { WAITVM(4); } else { WAITVM(0); }
        BAR();

        // ph e (qm0,qn0) buf1 — stage {A-h1,B-h0}(t0+2 -> buf0)
        loadA<0>(SA[1], af, wrow, fr, g);
        loadB<0>(SB[1], bf, wcol, fr, g);
        if (!last) { STG_A(1, t0 + 2, 0); STG_B(0, t0 + 2, 0); }
        BAR();
        __builtin_amdgcn_s_setprio(1);
        mfma16(af, bf, acc[0][0]);
        __builtin_amdgcn_s_setprio(0);
        BAR();

        // ph f (qm0,qn1) buf1
        loadB<1>(SB[1], bf, wcol, fr, g);
        BAR();
        __builtin_amdgcn_s_setprio(1);
        mfma16(af, bf, acc[0][1]);
        __builtin_amdgcn_s_setprio(0);
        BAR();

        // ph g (qm1,qn1) buf1 — stage A-h0(t0+3 -> buf1)
        loadA<1>(SA[1], af, wrow, fr, g);
        if (!last) STG_A(0, t0 + 3, 1);
        BAR();
        __builtin_amdgcn_s_setprio(1);
        mfma16(af, bf, acc[1][1]);
        __builtin_amdgcn_s_setprio(0);
        BAR();

        // ph h (qm1,qn0) buf1 — stage B-h1(t0+3 -> buf1); drain next tile's 8
        loadB<0>(SB[1], bf, wcol, fr, g);
        if (!last) STG_B(1, t0 + 3, 1);
        BAR();
        __builtin_amdgcn_s_setprio(1);
        mfma16(af, bf, acc[1][0]);
        __builtin_amdgcn_s_setprio(0);
        if (!last) WAITVM(4);
        BAR();
    }
#undef STG_A
#undef STG_B

    // C/D layout: col = lane&15, row = (lane>>4)*4 + reg  [verified m89/m91]
    const int cr = g * 4;

    float inv[2][4][4];
    if constexpr (EPI == 2) {
#pragma unroll
        for (int qm = 0; qm < 2; ++qm)
#pragma unroll
            for (int mi = 0; mi < 4; ++mi)
#pragma unroll
                for (int r = 0; r < 4; ++r)
                    inv[qm][mi][r] = 1.0f / rs[m0 + qm * 128 + wrow * 64 + mi * 16 + cr + r];
    }

    float rsume[2][4][4] = {};   // EPI==1 only (dead-code elsewhere)

#pragma unroll
    for (int qn = 0; qn < 2; ++qn)
#pragma unroll
    for (int ni = 0; ni < 2; ++ni) {
        const int col = n0 + qn * 128 + wcol * 32 + ni * 16 + fr;
        const float bv = (EPI == 0 && bias) ? bias[col] : 0.0f;
#pragma unroll
        for (int qm = 0; qm < 2; ++qm)
#pragma unroll
        for (int mi = 0; mi < 4; ++mi)
#pragma unroll
        for (int r = 0; r < 4; ++r) {
            const int row = m0 + qm * 128 + wrow * 64 + mi * 16 + cr + r;
            float v = acc[qm][qn][mi][ni][r];
            if constexpr (EPI == 0)      v = v * scale + bv;
            else if constexpr (EPI == 1) { v = __expf(v * scale); rsume[qm][mi][r] += v; }
            else                         v = v * inv[qm][mi][r];
            C[(long)row * ldc + col] = to_out<OutT>(v);
        }
    }

    if constexpr (EPI == 1) {
        // reduce over the 16 fr-lanes (cols), then one atomic per (row, wave)
#pragma unroll
        for (int qm = 0; qm < 2; ++qm)
#pragma unroll
        for (int mi = 0; mi < 4; ++mi)
#pragma unroll
        for (int r = 0; r < 4; ++r) {
            float s = rsume[qm][mi][r];
            s += __shfl_xor(s, 1, 64);
            s += __shfl_xor(s, 2, 64);
            s += __shfl_xor(s, 4, 64);
            s += __shfl_xor(s, 8, 64);
            if ((lane & 15) == 0)
                atomicAdd(&rs[m0 + qm * 128 + wrow * 64 + mi * 16 + cr + r], s);
        }
    }
}

extern "C" void kernel_launch(void* const* d_in, const int* in_sizes, int n_in,
                              void* d_out, int out_size, void* d_ws, size_t ws_size,
                              hipStream_t stream)
{
    const float* x     = (const float*)d_in[0];
    const float* w_qkv = (const float*)d_in[1];
    const float* b_qkv = (const float*)d_in[2];
    const float* w_prj = (const float*)d_in[3];
    const float* b_prj = (const float*)d_in[4];
    float* out = (float*)d_out;

    const float alpha = 1.0f / (sqrtf((float)DIM) * 3.0f);  // qk scale / temperature

    const size_t XE   = (size_t)B_BATCH * SEQ * DIM;
    const size_t WQE  = (size_t)E3 * DIM;
    const size_t WPE  = (size_t)DIM * DIM;
    const size_t QKVE = (size_t)B_BATCH * SEQ * E3;
    const size_t SE   = (size_t)B_BATCH * SEQ * SEQ;
    const size_t OE   = XE;
    const size_t RSE  = (size_t)B_BATCH * SEQ;             // fp32 row sums
    dim3 blk(256), blkg(512);

    const size_t full_bytes = (XE + WQE + WPE + QKVE + SE + OE) * sizeof(__hip_bfloat16)
                            + RSE * sizeof(float);

    if (ws_size >= full_bytes) {
        __hip_bfloat16* xb  = (__hip_bfloat16*)d_ws;
        __hip_bfloat16* wqb = xb + XE;
        __hip_bfloat16* wpb = wqb + WQE;
        __hip_bfloat16* qkv = wpb + WPE;
        __hip_bfloat16* S   = qkv + QKVE;
        __hip_bfloat16* O   = S + SE;
        float*          RS  = (float*)(O + OE);
        __hip_bfloat16* Vt  = xb;                      // xb dead after QKV GEMM

        cvt_f32_bf16<<<dim3((XE / 8 + 255) / 256), blk, 0, stream>>>(x, xb, XE / 8);
        cvt_f32_bf16<<<dim3((WQE / 8 + 255) / 256), blk, 0, stream>>>(w_qkv, wqb, WQE / 8);
        cvt_f32_bf16<<<dim3((WPE / 8 + 255) / 256), blk, 0, stream>>>(w_prj, wpb, WPE / 8);
        hipMemsetAsync(RS, 0, RSE * sizeof(float), stream);

        // qkv = x @ w_qkv^T + b   [16384 x 2304]  grid 576
        gemm256<__hip_bfloat16, 0><<<dim3(64 * 9), blkg, 0, stream>>>(
            xb, DIM, 0, wqb, DIM, 0, qkv, E3, 0, b_qkv, nullptr, 0, 1.0f, DIM, 64, 9);
        // Vt[b] = V[b]^T  [768 x 2048] per batch
        transpose64<<<dim3(SEQ / 64, DIM / 64, B_BATCH), blk, 0, stream>>>(
            qkv + 2 * DIM, E3, (long)SEQ * E3, Vt, SEQ, (long)DIM * SEQ);
        // E = exp(alpha * Q @ K^T), rowsums -> RS  [8][2048 x 2048]  grid 512
        gemm256<__hip_bfloat16, 1><<<dim3(8 * 8 * B_BATCH), blkg, 0, stream>>>(
            qkv, E3, (long)SEQ * E3, qkv + DIM, E3, (long)SEQ * E3,
            S, SEQ, (long)SEQ * SEQ, nullptr, RS, SEQ, alpha, DIM, 8, 8);
        // O = (E @ Vt^T) / RS[row]  [8][2048 x 768]  grid 192
        gemm256<__hip_bfloat16, 2><<<dim3(8 * 3 * B_BATCH), blkg, 0, stream>>>(
            S, SEQ, (long)SEQ * SEQ, Vt, SEQ, (long)DIM * SEQ,
            O, DIM, (long)SEQ * DIM, nullptr, RS, SEQ, 1.0f, SEQ, 8, 3);
        // out = O @ w_proj^T + b  [16384 x 768] fp32  grid 192
        gemm256<float, 0><<<dim3(64 * 3), blkg, 0, stream>>>(
            O, DIM, 0, wpb, DIM, 0, out, DIM, 0, b_prj, nullptr, 0, 1.0f, DIM, 64, 3);
    } else {
        // minimal-workspace fallback: per-batch pipeline (~30 MB scratch)
        const size_t xE  = (size_t)SEQ * DIM;
        const size_t qE  = (size_t)SEQ * E3;
        const size_t sE1 = (size_t)SEQ * SEQ;
        __hip_bfloat16* wqb = (__hip_bfloat16*)d_ws;
        __hip_bfloat16* wpb = wqb + WQE;
        __hip_bfloat16* xb  = wpb + WPE;            // reused as Vt per batch
        __hip_bfloat16* qkv = xb + xE;
        __hip_bfloat16* S   = qkv + qE;
        __hip_bfloat16* O   = S + sE1;
        float*          RS  = (float*)(O + xE);
        __hip_bfloat16* Vt  = xb;

        cvt_f32_bf16<<<dim3((WQE / 8 + 255) / 256), blk, 0, stream>>>(w_qkv, wqb, WQE / 8);
        cvt_f32_bf16<<<dim3((WPE / 8 + 255) / 256), blk, 0, stream>>>(w_prj, wpb, WPE / 8);

        for (int b = 0; b < B_BATCH; ++b) {
            const float* xf = x + (size_t)b * xE;
            cvt_f32_bf16<<<dim3((xE / 8 + 255) / 256), blk, 0, stream>>>(xf, xb, xE / 8);
            hipMemsetAsync(RS, 0, SEQ * sizeof(float), stream);
            gemm256<__hip_bfloat16, 0><<<dim3(8 * 9), blkg, 0, stream>>>(
                xb, DIM, 0, wqb, DIM, 0, qkv, E3, 0, b_qkv, nullptr, 0, 1.0f, DIM, 8, 9);
            transpose64<<<dim3(SEQ / 64, DIM / 64, 1), blk, 0, stream>>>(
                qkv + 2 * DIM, E3, 0, Vt, SEQ, 0);
            gemm256<__hip_bfloat16, 1><<<dim3(8 * 8), blkg, 0, stream>>>(
                qkv, E3, 0, qkv + DIM, E3, 0, S, SEQ, 0, nullptr, RS, 0, alpha, DIM, 8, 8);
            gemm256<__hip_bfloat16, 2><<<dim3(8 * 3), blkg, 0, stream>>>(
                S, SEQ, 0, Vt, SEQ, 0, O, DIM, 0, nullptr, RS, 0, 1.0f, SEQ, 8, 3);
            gemm256<float, 0><<<dim3(8 * 3), blkg, 0, stream>>>(
                O, DIM, 0, wpb, DIM, 0, out + (size_t)b * xE, DIM, 0, b_prj, nullptr, 0, 1.0f, DIM, 8, 3);
        }
    }
}